// Round 2
// baseline (653.480 us; speedup 1.0000x reference)
//
#include <hip/hip_runtime.h>
#include <math.h>

#define NEG_SLOPE 0.2f

static inline int cdiv(int a, int b) { return (a + b - 1) / b; }

// ================= CSR build (dst-sorted edge list, self-loops appended) ====

__global__ void hist_kernel(const int* __restrict__ dst, int* __restrict__ deg,
                            int E, int ET) {
    int e = blockIdx.x * blockDim.x + threadIdx.x;
    if (e >= ET) return;
    int d = (e < E) ? dst[e] : (e - E);
    atomicAdd(&deg[d], 1);
}

// per-block inclusive scan of deg -> incl, block totals -> bsum
__global__ void scan1_kernel(const int* __restrict__ deg, int* __restrict__ incl,
                             int* __restrict__ bsum, int N) {
    __shared__ int tmp[256];
    int i = blockIdx.x * 256 + threadIdx.x;
    int v = (i < N) ? deg[i] : 0;
    tmp[threadIdx.x] = v;
    __syncthreads();
    for (int off = 1; off < 256; off <<= 1) {
        int t = (threadIdx.x >= off) ? tmp[threadIdx.x - off] : 0;
        __syncthreads();
        tmp[threadIdx.x] += t;
        __syncthreads();
    }
    if (i < N) incl[i] = tmp[threadIdx.x];
    if (threadIdx.x == 255) bsum[blockIdx.x] = tmp[255];
}

// single-block exclusive scan of bsum (nb <= 256)
__global__ void scan2_kernel(int* __restrict__ bsum, int nb) {
    __shared__ int tmp[256];
    int v = (threadIdx.x < nb) ? bsum[threadIdx.x] : 0;
    tmp[threadIdx.x] = v;
    __syncthreads();
    for (int off = 1; off < 256; off <<= 1) {
        int t = (threadIdx.x >= off) ? tmp[threadIdx.x - off] : 0;
        __syncthreads();
        tmp[threadIdx.x] += t;
        __syncthreads();
    }
    if (threadIdx.x < nb) bsum[threadIdx.x] = tmp[threadIdx.x] - v;  // exclusive
}

// offs[i] = bsum[blk] + incl[i] - deg[i]   (exclusive row offsets)
__global__ void scan3_kernel(const int* __restrict__ incl, const int* __restrict__ deg,
                             const int* __restrict__ bsum, int* __restrict__ offs, int N) {
    int i = blockIdx.x * 256 + threadIdx.x;
    if (i >= N) return;
    offs[i] = bsum[blockIdx.x] + incl[i] - deg[i];
}

__global__ void scatter_kernel(const int* __restrict__ src, const int* __restrict__ dst,
                               const int* __restrict__ offs, int* __restrict__ cursor,
                               int* __restrict__ csr_src, int E, int ET) {
    int e = blockIdx.x * blockDim.x + threadIdx.x;
    if (e >= ET) return;
    int s = (e < E) ? src[e] : (e - E);
    int d = (e < E) ? dst[e] : (e - E);
    int pos = offs[d] + atomicAdd(&cursor[d], 1);
    csr_src[pos] = s;
}

// ================= dense GEMM: out[N,COUT] = in[N,CIN] @ W[CIN,COUT] ========
// 256 threads; each thread computes 4 contiguous outputs (float4 W loads).
template <int CIN, int COUT>
__global__ void gemm_kernel(const float* __restrict__ in, const float* __restrict__ W,
                            float* __restrict__ out, int N) {
    constexpr int TPN = COUT / 4;    // threads per node
    constexpr int NPB = 256 / TPN;   // nodes per block
    __shared__ float xs[NPB * CIN];
    int n0 = blockIdx.x * NPB;
    for (int i = threadIdx.x * 4; i < NPB * CIN; i += 256 * 4) {
        int n = n0 + i / CIN;
        float4 v = make_float4(0.f, 0.f, 0.f, 0.f);
        if (n < N) v = *(const float4*)&in[(size_t)n0 * CIN + i];
        *(float4*)&xs[i] = v;
    }
    __syncthreads();
    int tn = threadIdx.x / TPN;
    int tc = (threadIdx.x % TPN) * 4;
    int n = n0 + tn;
    if (n >= N) return;
    const float* xr = xs + tn * CIN;
    float4 a = make_float4(0.f, 0.f, 0.f, 0.f);
#pragma unroll 8
    for (int k = 0; k < CIN; ++k) {
        float xv = xr[k];
        float4 wv = *(const float4*)&W[k * COUT + tc];
        a.x = fmaf(xv, wv.x, a.x);
        a.y = fmaf(xv, wv.y, a.y);
        a.z = fmaf(xv, wv.z, a.z);
        a.w = fmaf(xv, wv.w, a.w);
    }
    *(float4*)&out[(size_t)n * COUT + tc] = a;
}

// ===== per-node attention logit halves: als[n,h]=<h[n,h,:],a_s[h,:]> =======
template <int H, int D>
__global__ void logits_kernel(const float* __restrict__ h, const float* __restrict__ a_s,
                              const float* __restrict__ a_d, float* __restrict__ als,
                              float* __restrict__ ald, int N) {
    int t = blockIdx.x * blockDim.x + threadIdx.x;
    if (t >= N * H) return;
    int n = t / H, hh = t % H;
    const float* hr = h + (size_t)n * (H * D) + hh * D;
    float s1 = 0.f, s2 = 0.f;
#pragma unroll
    for (int d = 0; d < D; ++d) {
        float v = hr[d];
        s1 = fmaf(v, a_s[hh * D + d], s1);
        s2 = fmaf(v, a_d[hh * D + d], s2);
    }
    als[t] = s1;
    ald[t] = s2;
}

// ===== fused per-node GAT aggregate: online softmax + weighted sum =========
// One wave handles 64/(H*D) nodes; lane c = h*D+d owns one output channel.
// No atomics; epilogue fuses /s + bias (+ReLU).
template <int H, int D, bool RELU>
__global__ void gat_aggregate(const float* __restrict__ hfeat,
                              const float* __restrict__ als, const float* __restrict__ ald,
                              const int* __restrict__ offs, const int* __restrict__ deg,
                              const int* __restrict__ csr_src,
                              const float* __restrict__ bias,
                              float* __restrict__ out, int N) {
    constexpr int HD = H * D;
    constexpr int NPW = 64 / HD;  // nodes per wave
    int lane = threadIdx.x & 63;
    int wid = threadIdx.x >> 6;
    int wavesPerBlock = blockDim.x >> 6;
    int grp = lane / HD;
    int c = lane % HD;
    int h = c / D;
    long node = ((long)blockIdx.x * wavesPerBlock + wid) * NPW + grp;
    if (node >= N) return;
    int row = offs[node];
    int cnt = deg[node];
    float xd = ald[node * H + h];
    float m = -INFINITY, s = 0.f, acc = 0.f;
#pragma unroll 4
    for (int k = 0; k < cnt; ++k) {
        int sn = csr_src[row + k];
        float x = als[sn * H + h] + xd;
        x = (x > 0.f) ? x : NEG_SLOPE * x;
        float hv = hfeat[(size_t)sn * HD + c];
        float mn = fmaxf(m, x);
        float sc = __expf(m - mn);
        float w = __expf(x - mn);
        s = s * sc + w;
        acc = acc * sc + w * hv;
        m = mn;
    }
    float v = acc / s + bias[c];
    if (RELU) v = fmaxf(v, 0.f);
    out[(size_t)node * HD + c] = v;
}

// ============================================================================

extern "C" void kernel_launch(void* const* d_in, const int* in_sizes, int n_in,
                              void* d_out, int out_size, void* d_ws, size_t ws_size,
                              hipStream_t stream) {
    const float* x   = (const float*)d_in[0];
    const int*   ei  = (const int*)d_in[1];
    const float* W1  = (const float*)d_in[2];
    const float* a1s = (const float*)d_in[3];
    const float* a1d = (const float*)d_in[4];
    const float* b1  = (const float*)d_in[5];
    const float* W2  = (const float*)d_in[6];
    const float* a2s = (const float*)d_in[7];
    const float* a2d = (const float*)d_in[8];
    const float* b2  = (const float*)d_in[9];
    const float* W3  = (const float*)d_in[10];
    const float* a3s = (const float*)d_in[11];
    const float* a3d = (const float*)d_in[12];
    const float* b3  = (const float*)d_in[13];
    const float* W4  = (const float*)d_in[14];
    const float* a4s = (const float*)d_in[15];
    const float* a4d = (const float*)d_in[16];
    const float* b4  = (const float*)d_in[17];

    const int N = in_sizes[0] / 128;  // 50000
    const int E = in_sizes[1] / 2;    // 1600000
    const int ET = E + N;             // + self loops
    const int* src = ei;
    const int* dst = ei + E;

    // ---- workspace layout ----
    float* hb   = (float*)d_ws;                   // N*64
    float* bufA = hb + (size_t)N * 64;            // N*64
    float* bufB = bufA + (size_t)N * 64;          // N*64
    float* als  = bufB + (size_t)N * 64;          // N*8
    float* ald  = als + (size_t)N * 8;            // N*8
    int* deg    = (int*)(ald + (size_t)N * 8);    // N
    int* offs   = deg + N;                        // N
    int* incl   = offs + N;                       // N (scan temp)
    int* bsum   = incl + N;                       // 256
    int* cursor = bsum + 256;                     // N
    int* csr_src = cursor + N;                    // ET
    float* out = (float*)d_out;                   // N*16

    const int TB = 256;
    const int nb = cdiv(N, 256);  // scan blocks (196 <= 256)

    // ---- build dst-CSR once per launch ----
    hipMemsetAsync(deg, 0, (size_t)N * 4, stream);
    hist_kernel<<<cdiv(ET, TB), TB, 0, stream>>>(dst, deg, E, ET);
    scan1_kernel<<<nb, 256, 0, stream>>>(deg, incl, bsum, N);
    scan2_kernel<<<1, 256, 0, stream>>>(bsum, nb);
    scan3_kernel<<<nb, 256, 0, stream>>>(incl, deg, bsum, offs, N);
    hipMemsetAsync(cursor, 0, (size_t)N * 4, stream);
    scatter_kernel<<<cdiv(ET, TB), TB, 0, stream>>>(src, dst, offs, cursor, csr_src, E, ET);

    // ---- layer 1: x[N,128] -> bufA[N,64] ----
    gemm_kernel<128, 64><<<cdiv(N, 16), TB, 0, stream>>>(x, W1, hb, N);
    logits_kernel<8, 8><<<cdiv(N * 8, TB), TB, 0, stream>>>(hb, a1s, a1d, als, ald, N);
    gat_aggregate<8, 8, true><<<cdiv(N, 4), TB, 0, stream>>>(hb, als, ald, offs, deg, csr_src, b1, bufA, N);

    // ---- layer 2: bufA -> bufB ----
    gemm_kernel<64, 64><<<cdiv(N, 16), TB, 0, stream>>>(bufA, W2, hb, N);
    logits_kernel<8, 8><<<cdiv(N * 8, TB), TB, 0, stream>>>(hb, a2s, a2d, als, ald, N);
    gat_aggregate<8, 8, true><<<cdiv(N, 4), TB, 0, stream>>>(hb, als, ald, offs, deg, csr_src, b2, bufB, N);

    // ---- layer 3: bufB -> bufA ----
    gemm_kernel<64, 64><<<cdiv(N, 16), TB, 0, stream>>>(bufB, W3, hb, N);
    logits_kernel<8, 8><<<cdiv(N * 8, TB), TB, 0, stream>>>(hb, a3s, a3d, als, ald, N);
    gat_aggregate<8, 8, true><<<cdiv(N, 4), TB, 0, stream>>>(hb, als, ald, offs, deg, csr_src, b3, bufA, N);

    // ---- layer 4: bufA -> d_out[N,16]  (H=1, D=16, no relu) ----
    gemm_kernel<64, 16><<<cdiv(N, 64), TB, 0, stream>>>(bufA, W4, hb, N);
    logits_kernel<1, 16><<<cdiv(N, TB), TB, 0, stream>>>(hb, a4s, a4d, als, ald, N);
    gat_aggregate<1, 16, false><<<cdiv(N, 16), TB, 0, stream>>>(hb, als, ald, offs, deg, csr_src, b4, out, N);
}

// Round 3
// 584.574 us; speedup vs baseline: 1.1179x; 1.1179x over previous
//
#include <hip/hip_runtime.h>
#include <math.h>

#define NEG_SLOPE 0.2f

static inline int cdiv(int a, int b) { return (a + b - 1) / b; }

// Bucketed CSR build parameters. Bucket = 64 consecutive dst nodes.
// Packing (src<<6)|dst_local requires N <= 65536 (here N = 50000).
#define SUB 8
#define SUBCAP 768
#define CAP (SUB * SUBCAP)   // 6144 entries per bucket
#define OVF_CAP 32768

// ===================== pass 1: append edges to dst-buckets ==================
__global__ void bucket_append(const int* __restrict__ src, const int* __restrict__ dst,
                              unsigned* __restrict__ bcnt, unsigned* __restrict__ slab,
                              uint2* __restrict__ ovf, unsigned* __restrict__ ovf_cnt,
                              int E, int ET) {
    int e = blockIdx.x * blockDim.x + threadIdx.x;
    if (e >= ET) return;
    int s = (e < E) ? src[e] : (e - E);
    int d = (e < E) ? dst[e] : (e - E);
    int b = d >> 6;
    int dl = d & 63;
    int sub = e & (SUB - 1);
    unsigned idx = atomicAdd(&bcnt[b * SUB + sub], 1u);
    if (idx < SUBCAP) {
        slab[(size_t)b * CAP + sub * SUBCAP + idx] = ((unsigned)s << 6) | (unsigned)dl;
    } else {
        unsigned o = atomicAdd(ovf_cnt, 1u);
        if (o < OVF_CAP) ovf[o] = make_uint2((unsigned)s, (unsigned)d);
    }
}

// ===================== pass 2a: per-bucket degree via LDS hist ==============
__global__ void bucket_deg(const unsigned* __restrict__ bcnt, const unsigned* __restrict__ slab,
                           int* __restrict__ deg, int N) {
    int b = blockIdx.x;
    int d0 = b << 6;
    __shared__ int lhist[64];
    if (threadIdx.x < 64) lhist[threadIdx.x] = 0;
    __syncthreads();
    for (int sub = 0; sub < SUB; ++sub) {
        unsigned cnt = min(bcnt[b * SUB + sub], (unsigned)SUBCAP);
        const unsigned* sp = slab + (size_t)b * CAP + sub * SUBCAP;
        for (unsigned i = threadIdx.x; i < cnt; i += blockDim.x)
            atomicAdd(&lhist[sp[i] & 63u], 1);
    }
    __syncthreads();
    if (threadIdx.x < 64 && d0 + (int)threadIdx.x < N)
        deg[d0 + threadIdx.x] = lhist[threadIdx.x];
}

// overflow edges also count toward degree (normally zero work)
__global__ void ovf_deg_kernel(const uint2* __restrict__ ovf, const unsigned* __restrict__ ovf_cnt,
                               int* __restrict__ deg) {
    unsigned n = min(*ovf_cnt, (unsigned)OVF_CAP);
    unsigned i = blockIdx.x * blockDim.x + threadIdx.x;
    if (i < n) atomicAdd(&deg[ovf[i].y], 1);
}

// ===================== scans (deg -> exclusive offs) ========================
__global__ void scan1_kernel(const int* __restrict__ deg, int* __restrict__ incl,
                             int* __restrict__ bsum, int N) {
    __shared__ int tmp[256];
    int i = blockIdx.x * 256 + threadIdx.x;
    int v = (i < N) ? deg[i] : 0;
    tmp[threadIdx.x] = v;
    __syncthreads();
    for (int off = 1; off < 256; off <<= 1) {
        int t = (threadIdx.x >= off) ? tmp[threadIdx.x - off] : 0;
        __syncthreads();
        tmp[threadIdx.x] += t;
        __syncthreads();
    }
    if (i < N) incl[i] = tmp[threadIdx.x];
    if (threadIdx.x == 255) bsum[blockIdx.x] = tmp[255];
}

__global__ void scan2_kernel(int* __restrict__ bsum, int nb) {
    __shared__ int tmp[256];
    int v = (threadIdx.x < nb) ? bsum[threadIdx.x] : 0;
    tmp[threadIdx.x] = v;
    __syncthreads();
    for (int off = 1; off < 256; off <<= 1) {
        int t = (threadIdx.x >= off) ? tmp[threadIdx.x - off] : 0;
        __syncthreads();
        tmp[threadIdx.x] += t;
        __syncthreads();
    }
    if (threadIdx.x < nb) bsum[threadIdx.x] = tmp[threadIdx.x] - v;  // exclusive
}

__global__ void scan3_kernel(const int* __restrict__ incl, const int* __restrict__ deg,
                             const int* __restrict__ bsum, int* __restrict__ offs, int N) {
    int i = blockIdx.x * 256 + threadIdx.x;
    if (i >= N) return;
    offs[i] = bsum[blockIdx.x] + incl[i] - deg[i];
}

// ========== pass 2b: place bucket edges into contiguous CSR slab ============
__global__ void bucket_place(const unsigned* __restrict__ bcnt, const unsigned* __restrict__ slab,
                             const int* __restrict__ offs, int* __restrict__ cursor,
                             int* __restrict__ csr_src, int N, int ET) {
    int b = blockIdx.x;
    int d0 = b << 6;
    int nd = min(64, N - d0);
    __shared__ int loffs[65];
    __shared__ int lcur[64];
    __shared__ int stage[4096];
    if (threadIdx.x <= 64) {
        int d = d0 + threadIdx.x;
        loffs[threadIdx.x] = (d < N) ? offs[d] : ET;
    }
    if (threadIdx.x < 64) lcur[threadIdx.x] = 0;
    __syncthreads();
    int base = loffs[0];
    int span = loffs[nd] - base;
    if (span <= 4096) {
        for (int sub = 0; sub < SUB; ++sub) {
            unsigned cnt = min(bcnt[b * SUB + sub], (unsigned)SUBCAP);
            const unsigned* sp = slab + (size_t)b * CAP + sub * SUBCAP;
            for (unsigned i = threadIdx.x; i < cnt; i += blockDim.x) {
                unsigned v = sp[i];
                int dl = v & 63u;
                int r = atomicAdd(&lcur[dl], 1);
                stage[(loffs[dl] - base) + r] = (int)(v >> 6);
            }
        }
        __syncthreads();
        for (int i = threadIdx.x; i < span; i += blockDim.x)
            csr_src[base + i] = stage[i];
        if (threadIdx.x < nd) cursor[d0 + threadIdx.x] = lcur[threadIdx.x];
    } else {
        // fallback (extreme skew): direct global scatter, cursor pre-zeroed
        for (int sub = 0; sub < SUB; ++sub) {
            unsigned cnt = min(bcnt[b * SUB + sub], (unsigned)SUBCAP);
            const unsigned* sp = slab + (size_t)b * CAP + sub * SUBCAP;
            for (unsigned i = threadIdx.x; i < cnt; i += blockDim.x) {
                unsigned v = sp[i];
                int d = d0 + (int)(v & 63u);
                int pos = offs[d] + atomicAdd(&cursor[d], 1);
                csr_src[pos] = (int)(v >> 6);
            }
        }
    }
}

__global__ void ovf_place_kernel(const uint2* __restrict__ ovf, const unsigned* __restrict__ ovf_cnt,
                                 const int* __restrict__ offs, int* __restrict__ cursor,
                                 int* __restrict__ csr_src) {
    unsigned n = min(*ovf_cnt, (unsigned)OVF_CAP);
    unsigned i = blockIdx.x * blockDim.x + threadIdx.x;
    if (i < n) {
        int s = (int)ovf[i].x, d = (int)ovf[i].y;
        int pos = offs[d] + atomicAdd(&cursor[d], 1);
        csr_src[pos] = s;
    }
}

// ============ dense GEMM + fused attention-logit epilogue ===================
// out[N,COUT] = in[N,CIN] @ W[CIN,COUT]; als/ald[n,h] = <h[n,h,:], a_s/a_d[h,:]>
template <int CIN, int COUT, int H>
__global__ void gemm_logits_kernel(const float* __restrict__ in, const float* __restrict__ W,
                                   const float* __restrict__ a_s, const float* __restrict__ a_d,
                                   float* __restrict__ out, float* __restrict__ als,
                                   float* __restrict__ ald, int N) {
    constexpr int D = COUT / H;
    constexpr int TPN = COUT / 4;    // threads per node
    constexpr int NPB = 256 / TPN;   // nodes per block
    __shared__ float xs[NPB * CIN];
    __shared__ float lsum[2][NPB][H];
    int n0 = blockIdx.x * NPB;
    for (int i = threadIdx.x * 4; i < NPB * CIN; i += 256 * 4) {
        int n = n0 + i / CIN;
        float4 v = make_float4(0.f, 0.f, 0.f, 0.f);
        if (n < N) v = *(const float4*)&in[(size_t)n0 * CIN + i];
        *(float4*)&xs[i] = v;
    }
    for (int i = threadIdx.x; i < 2 * NPB * H; i += 256) ((float*)lsum)[i] = 0.f;
    __syncthreads();
    int tn = threadIdx.x / TPN;
    int tc = (threadIdx.x % TPN) * 4;
    int n = n0 + tn;
    if (n < N) {
        const float* xr = xs + tn * CIN;
        float4 a = make_float4(0.f, 0.f, 0.f, 0.f);
#pragma unroll 8
        for (int k = 0; k < CIN; ++k) {
            float xv = xr[k];
            float4 wv = *(const float4*)&W[k * COUT + tc];
            a.x = fmaf(xv, wv.x, a.x);
            a.y = fmaf(xv, wv.y, a.y);
            a.z = fmaf(xv, wv.z, a.z);
            a.w = fmaf(xv, wv.w, a.w);
        }
        *(float4*)&out[(size_t)n * COUT + tc] = a;
        int h = tc / D;          // 4 contiguous channels lie in one head (D % 4 == 0)
        int dd = tc % D;
        const float* asr = a_s + h * D + dd;
        const float* adr = a_d + h * D + dd;
        float p1 = a.x * asr[0] + a.y * asr[1] + a.z * asr[2] + a.w * asr[3];
        float p2 = a.x * adr[0] + a.y * adr[1] + a.z * adr[2] + a.w * adr[3];
        atomicAdd(&lsum[0][tn][h], p1);
        atomicAdd(&lsum[1][tn][h], p2);
    }
    __syncthreads();
    for (int i = threadIdx.x; i < NPB * H; i += 256) {
        int tn2 = i / H, h2 = i % H;
        int n2 = n0 + tn2;
        if (n2 < N) {
            als[n2 * H + h2] = lsum[0][tn2][h2];
            ald[n2 * H + h2] = lsum[1][tn2][h2];
        }
    }
}

// ===== fused per-node GAT aggregate: online softmax + weighted sum =========
template <int H, int D, bool RELU>
__global__ void gat_aggregate(const float* __restrict__ hfeat,
                              const float* __restrict__ als, const float* __restrict__ ald,
                              const int* __restrict__ offs, const int* __restrict__ deg,
                              const int* __restrict__ csr_src,
                              const float* __restrict__ bias,
                              float* __restrict__ out, int N) {
    constexpr int HD = H * D;
    constexpr int NPW = 64 / HD;  // nodes per wave
    int lane = threadIdx.x & 63;
    int wid = threadIdx.x >> 6;
    int wavesPerBlock = blockDim.x >> 6;
    int grp = lane / HD;
    int c = lane % HD;
    int h = c / D;
    long node = ((long)blockIdx.x * wavesPerBlock + wid) * NPW + grp;
    if (node >= N) return;
    int row = offs[node];
    int cnt = deg[node];
    float xd = ald[node * H + h];
    float m = -INFINITY, s = 0.f, acc = 0.f;
#pragma unroll 4
    for (int k = 0; k < cnt; ++k) {
        int sn = csr_src[row + k];
        float x = als[sn * H + h] + xd;
        x = (x > 0.f) ? x : NEG_SLOPE * x;
        float hv = hfeat[(size_t)sn * HD + c];
        float mn = fmaxf(m, x);
        float sc = __expf(m - mn);
        float w = __expf(x - mn);
        s = s * sc + w;
        acc = acc * sc + w * hv;
        m = mn;
    }
    float v = acc / s + bias[c];
    if (RELU) v = fmaxf(v, 0.f);
    out[(size_t)node * HD + c] = v;
}

// ============================================================================

extern "C" void kernel_launch(void* const* d_in, const int* in_sizes, int n_in,
                              void* d_out, int out_size, void* d_ws, size_t ws_size,
                              hipStream_t stream) {
    const float* x   = (const float*)d_in[0];
    const int*   ei  = (const int*)d_in[1];
    const float* W1  = (const float*)d_in[2];
    const float* a1s = (const float*)d_in[3];
    const float* a1d = (const float*)d_in[4];
    const float* b1  = (const float*)d_in[5];
    const float* W2  = (const float*)d_in[6];
    const float* a2s = (const float*)d_in[7];
    const float* a2d = (const float*)d_in[8];
    const float* b2  = (const float*)d_in[9];
    const float* W3  = (const float*)d_in[10];
    const float* a3s = (const float*)d_in[11];
    const float* a3d = (const float*)d_in[12];
    const float* b3  = (const float*)d_in[13];
    const float* W4  = (const float*)d_in[14];
    const float* a4s = (const float*)d_in[15];
    const float* a4d = (const float*)d_in[16];
    const float* b4  = (const float*)d_in[17];

    const int N = in_sizes[0] / 128;  // 50000
    const int E = in_sizes[1] / 2;    // 1600000
    const int ET = E + N;             // + self loops
    const int* src = ei;
    const int* dst = ei + E;
    const int NB = (N + 63) >> 6;     // buckets (782)

    // ---- workspace layout ----
    float* hb    = (float*)d_ws;                    // N*64
    float* bufA  = hb + (size_t)N * 64;             // N*64
    float* als   = bufA + (size_t)N * 64;           // N*8
    float* ald   = als + (size_t)N * 8;             // N*8
    // zero-region: cursor | bcnt | ovf_cnt (single memset)
    int* cursor      = (int*)(ald + (size_t)N * 8); // N
    unsigned* bcnt   = (unsigned*)(cursor + N);     // NB*SUB
    unsigned* ovf_cnt = bcnt + (size_t)NB * SUB;    // 1 (+pad 15)
    int* deg    = (int*)(ovf_cnt + 16);             // N
    int* incl   = deg + N;                          // N
    int* bsum   = incl + N;                         // 256
    int* offs   = bsum + 256;                       // N
    unsigned* slab = (unsigned*)(offs + N);         // NB*CAP
    uint2* ovf  = (uint2*)(slab + (size_t)NB * CAP);// OVF_CAP
    int* csr_src = (int*)(ovf + OVF_CAP);           // ET
    float* out = (float*)d_out;                     // N*16

    const int TB = 256;
    const int nb_scan = cdiv(N, 256);

    // ---- build dst-CSR (bucketed, no global-memory scatter/atomic hist) ----
    hipMemsetAsync(cursor, 0, ((size_t)N + (size_t)NB * SUB + 16) * 4, stream);
    bucket_append<<<cdiv(ET, TB), TB, 0, stream>>>(src, dst, bcnt, slab, ovf, ovf_cnt, E, ET);
    bucket_deg<<<NB, TB, 0, stream>>>(bcnt, slab, deg, N);
    ovf_deg_kernel<<<cdiv(OVF_CAP, TB), TB, 0, stream>>>(ovf, ovf_cnt, deg);
    scan1_kernel<<<nb_scan, 256, 0, stream>>>(deg, incl, bsum, N);
    scan2_kernel<<<1, 256, 0, stream>>>(bsum, nb_scan);
    scan3_kernel<<<nb_scan, 256, 0, stream>>>(incl, deg, bsum, offs, N);
    bucket_place<<<NB, TB, 0, stream>>>(bcnt, slab, offs, cursor, csr_src, N, ET);
    ovf_place_kernel<<<cdiv(OVF_CAP, TB), TB, 0, stream>>>(ovf, ovf_cnt, offs, cursor, csr_src);

    // ---- layer 1: x[N,128] -> hb -> bufA ----
    gemm_logits_kernel<128, 64, 8><<<cdiv(N, 16), TB, 0, stream>>>(x, W1, a1s, a1d, hb, als, ald, N);
    gat_aggregate<8, 8, true><<<cdiv(N, 4), TB, 0, stream>>>(hb, als, ald, offs, deg, csr_src, b1, bufA, N);

    // ---- layer 2: bufA -> hb -> bufA ----
    gemm_logits_kernel<64, 64, 8><<<cdiv(N, 16), TB, 0, stream>>>(bufA, W2, a2s, a2d, hb, als, ald, N);
    gat_aggregate<8, 8, true><<<cdiv(N, 4), TB, 0, stream>>>(hb, als, ald, offs, deg, csr_src, b2, bufA, N);

    // ---- layer 3: bufA -> hb -> bufA ----
    gemm_logits_kernel<64, 64, 8><<<cdiv(N, 16), TB, 0, stream>>>(bufA, W3, a3s, a3d, hb, als, ald, N);
    gat_aggregate<8, 8, true><<<cdiv(N, 4), TB, 0, stream>>>(hb, als, ald, offs, deg, csr_src, b3, bufA, N);

    // ---- layer 4: bufA -> hb -> d_out (H=1, D=16, no relu) ----
    gemm_logits_kernel<64, 16, 1><<<cdiv(N, 64), TB, 0, stream>>>(bufA, W4, a4s, a4d, hb, als, ald, N);
    gat_aggregate<1, 16, false><<<cdiv(N, 16), TB, 0, stream>>>(hb, als, ald, offs, deg, csr_src, b4, out, N);
}